// Round 1
// baseline (424.494 us; speedup 1.0000x reference)
//
#include <hip/hip_runtime.h>
#include <hip/hip_bf16.h>

#define S_LEN 4096
#define EMB   768
#define NH    12
#define DH    64
#define NCHUNK 4
#define CKL2   10         // chunk keys = 1024

#define LOG2E 1.44269504088896f

// finite sentinel instead of -INFINITY: safe under fast-math builds
#define NEG_BIG (-1e30f)

// HW 2^x (v_exp_f32); __exp2f does not exist in HIP device code
#define EXP2F(x) __builtin_amdgcn_exp2f(x)

using bf16x8 = __attribute__((ext_vector_type(8))) short;
using bf16x4 = __attribute__((ext_vector_type(4))) short;
using f32x4  = __attribute__((ext_vector_type(4))) float;

__device__ __forceinline__ short f2bf(float f) {
    __hip_bfloat16 h = __float2bfloat16(f);
    short s; __builtin_memcpy(&s, &h, 2); return s;
}
__device__ __forceinline__ float bf2f(short s) {
    __hip_bfloat16 h; __builtin_memcpy(&h, &s, 2);
    return __bfloat162float(h);
}

// pack two f32 -> two bf16 (round-half-up) in one u32 via v_perm_b32
__device__ __forceinline__ unsigned pack_bf16_rh(float a, float b) {
    unsigned ua, ub;
    __builtin_memcpy(&ua, &a, 4);
    __builtin_memcpy(&ub, &b, 4);
    return __builtin_amdgcn_perm(ub + 0x8000u, ua + 0x8000u, 0x07060302u);
}

// async global->LDS, 16B per lane; lds dest = uniform base + lane*16
__device__ __forceinline__ void gld_lds16(const void* g, void* l) {
    __builtin_amdgcn_global_load_lds(
        (const __attribute__((address_space(1))) unsigned int*)g,
        (__attribute__((address_space(3))) unsigned int*)l, 16, 0, 0);
}

__device__ __forceinline__ void cvt8(const float* s, short* d, int i) {
    const float4 a = ((const float4*)s)[i * 2];
    const float4 b = ((const float4*)s)[i * 2 + 1];
    bf16x8 o;
    o[0] = f2bf(a.x); o[1] = f2bf(a.y); o[2] = f2bf(a.z); o[3] = f2bf(a.w);
    o[4] = f2bf(b.x); o[5] = f2bf(b.y); o[6] = f2bf(b.z); o[7] = f2bf(b.w);
    ((bf16x8*)d)[i] = o;
}

// ---------------------------------------------------------------------------
// Kernel 0a/0b: fp32 -> bf16 converts
// ---------------------------------------------------------------------------
__global__ __launch_bounds__(256) void cvt_bf16(
    const float* __restrict__ s, short* __restrict__ d, int n8)
{
    const int i = blockIdx.x * 256 + threadIdx.x;
    if (i < n8) cvt8(s, d, i);
}

__global__ __launch_bounds__(256) void cvt3_bf16(
    const float* __restrict__ x,  short* __restrict__ xb,  int n8x,
    const float* __restrict__ wq, short* __restrict__ wqb, int n8q,
    const float* __restrict__ wo, short* __restrict__ wob, int n8o)
{
    int i = blockIdx.x * 256 + threadIdx.x;
    if (i < n8x) { cvt8(x, xb, i); return; }
    i -= n8x;
    if (i < n8q) { cvt8(wq, wqb, i); return; }
    i -= n8q;
    if (i < n8o) cvt8(wo, wob, i);
}

// ---------------------------------------------------------------------------
// Kernel 1: QKV projection, bf16 inputs, global_load_lds staging.
// V-part tiles transpose C through LDS -> fully COALESCED Vt writes.
// Q pre-scaled by log2(e) so flash uses exp2 (1 instr).
// ---------------------------------------------------------------------------
__global__ __launch_bounds__(256) void qkv_gemm(
    const short* __restrict__ Xb, const short* __restrict__ Wb,
    const float* __restrict__ Bias,
    short* __restrict__ Qw, short* __restrict__ Kw, short* __restrict__ Vt)
{
    __shared__ __align__(16) short SMEM[2 * 128 * 64];  // As | Bs ; reused as T
    short* As = SMEM;
    short* Bs = SMEM + 128 * 64;

    const int m0 = blockIdx.x * 128;
    const int n0 = blockIdx.y * 128;
    const int t = threadIdx.x;
    const int lane = t & 63, wave = t >> 6;
    const int quad = lane >> 4, l16 = lane & 15;
    const int wm = (wave >> 1) * 64, wn = (wave & 1) * 64;
    const int srow = lane >> 3, scol = (lane & 7) * 8;

    f32x4 acc[4][4] = {};

    for (int k0 = 0; k0 < EMB; k0 += 64) {
        #pragma unroll
        for (int qd = 0; qd < 4; qd++) {
            const int chunk = wave * 4 + qd;
            const int row = chunk * 8 + srow;
            gld_lds16(&Xb[(size_t)(m0 + row) * EMB + k0 + scol], &As[chunk * 512]);
            gld_lds16(&Wb[(size_t)(n0 + row) * EMB + k0 + scol], &Bs[chunk * 512]);
        }
        __syncthreads();

        #pragma unroll
        for (int kb = 0; kb < 2; kb++) {
            bf16x8 af[4], bfr[4];
            #pragma unroll
            for (int i = 0; i < 4; i++)
                af[i] = *(const bf16x8*)&As[(wm + i * 16 + l16) * 64 + kb * 32 + quad * 8];
            #pragma unroll
            for (int j = 0; j < 4; j++)
                bfr[j] = *(const bf16x8*)&Bs[(wn + j * 16 + l16) * 64 + kb * 32 + quad * 8];
            #pragma unroll
            for (int i = 0; i < 4; i++)
                #pragma unroll
                for (int j = 0; j < 4; j++)
                    acc[i][j] = __builtin_amdgcn_mfma_f32_16x16x32_bf16(
                        af[i], bfr[j], acc[i][j], 0, 0, 0);
        }
        __syncthreads();
    }

    const int part = n0 / EMB;           // block-uniform: 0=Q 1=K 2=V

    if (part < 2) {
        // Q/K: Q scaled by log2e for exp2-domain softmax.
        const float qs = (part == 0) ? LOG2E : 1.0f;
        #pragma unroll
        for (int j = 0; j < 4; j++) {
            const int n = n0 + wn + j * 16 + l16;
            const float bias = Bias[n];
            const int r768 = n % EMB;
            const int h = r768 >> 6, d = r768 & 63;
            short* dst = (part == 0) ? Qw : Kw;
            #pragma unroll
            for (int i = 0; i < 4; i++)
                #pragma unroll
                for (int r = 0; r < 4; r++) {
                    const int m = m0 + wm + i * 16 + quad * 4 + r;
                    dst[((size_t)h * S_LEN + m) * DH + d] =
                        f2bf((acc[i][j][r] + bias) * qs);
                }
        }
    } else {
        // V: transpose C-tile through LDS T[128 n][128 m], coalesced Vt rows.
        #pragma unroll
        for (int j = 0; j < 4; j++) {
            const int nl = wn + j * 16 + l16;
            const float bias = Bias[n0 + nl];
            #pragma unroll
            for (int i = 0; i < 4; i++) {
                short4 v;
                v.x = f2bf(acc[i][j][0] + bias);
                v.y = f2bf(acc[i][j][1] + bias);
                v.z = f2bf(acc[i][j][2] + bias);
                v.w = f2bf(acc[i][j][3] + bias);
                *(short4*)&SMEM[nl * 128 + wm + i * 16 + quad * 4] = v;
            }
        }
        __syncthreads();
        const int vrow0 = n0 - 2 * EMB;          // Vt row base = h*64+d = r768
        #pragma unroll
        for (int c = t; c < 2048; c += 256) {    // 2048 chunks = 128 rows x 128 m
            const int row = c >> 4, off = (c & 15) * 8;
            *(bf16x8*)&Vt[(size_t)(vrow0 + row) * S_LEN + m0 + off] =
                *(const bf16x8*)&SMEM[row * 128 + off];
        }
    }
}

// ---------------------------------------------------------------------------
// Kernel 2a: split-K flash partial — LDS-FREE rewrite.
//   * K/V working set is L2-resident (512 KB each per head); staging it in
//     LDS cost 9.77M bank-conflict cycles + 2 barriers/k-tile (measured:
//     MfmaUtil 14%, VALUBusy 39%, HBM 7.6% -> latency/conflict-bound).
//     All K/Vt fragments now load straight from global (L1/L2 hits).
//   * Full-K=32 PV MFMA: two 16-key sub-blocks packed per MFMA (was half-
//     empty K=16 -> PV MFMA count halves).
//   * 32 q-rows per wave (2 q-frags share every K/V fragment) -> fragment
//     traffic per q-row halves. 128 threads / 2 waves per block, grid
//     unchanged (S/64, NH, NCHUNK); merge kernel unchanged.
//   * Heavy-first dispatch: qt reversed so nk=8 blocks start first.
// ---------------------------------------------------------------------------
__global__ __launch_bounds__(128) void flash_partial(
    const short* __restrict__ Qw, const short* __restrict__ Kw,
    const short* __restrict__ Vt,
    short* __restrict__ Opart, float* __restrict__ Mpart,
    float* __restrict__ Lpart)
{
    const int qt = (gridDim.x - 1) - blockIdx.x;   // heavy-first
    const int h  = blockIdx.y;
    const int kc = blockIdx.z;
    const int q0  = qt * 64;
    const int ks0 = kc << CKL2;
    if (ks0 > q0) return;
    const int KIT = (1 << CKL2) / 128;   // 8
    const int T  = q0 >> 7;
    const int nk = min(KIT, T - KIT * kc + 1);

    const int t = threadIdx.x;
    const int lane = t & 63, wave = t >> 6;        // wave in {0,1}
    const int quad = lane >> 4, l16 = lane & 15;
    const int qw0 = q0 + wave * 32;                // this wave's 32 q rows

    const short* Kh = Kw + (size_t)h * S_LEN * DH;
    const short* Vh = Vt + (size_t)h * DH * S_LEN;

    // Q fragments: i selects 16-row q sub-block
    bf16x8 qf[2][2];
    #pragma unroll
    for (int i = 0; i < 2; i++)
        #pragma unroll
        for (int kb = 0; kb < 2; kb++)
            qf[i][kb] = *(const bf16x8*)
                &Qw[((size_t)h * S_LEN + qw0 + i * 16 + l16) * DH + kb * 32 + quad * 8];

    float m_i[2] = {NEG_BIG, NEG_BIG}, l_i[2] = {0.f, 0.f};
    f32x4 o_acc[2][4] = {};

    for (int kt = 0; kt < nk; kt++) {
        const int k0 = ks0 + kt * 128;
        const bool maskn = (k0 + 127 > q0);

        #pragma unroll
        for (int sub = 0; sub < 2; sub++) {
            const int kbase = k0 + sub * 64;
            if (maskn && kbase > qw0 + 31) continue;          // wave fully masked
            const bool a0 = !(maskn && kbase > qw0 + 15);     // i=0 rows active?

            // ---- QK^T: sfT[i][bb][r] = score(key=kbase+bb*16+quad*4+r,
            //                                  q=qw0+i*16+l16), direct-global K
            f32x4 sfT[2][4] = {};
            #pragma unroll
            for (int bb = 0; bb < 4; bb++) {
                #pragma unroll
                for (int kb = 0; kb < 2; kb++) {
                    const bf16x8 kf = *(const bf16x8*)
                        &Kh[(size_t)(kbase + bb * 16 + l16) * DH + kb * 32 + quad * 8];
                    sfT[0][bb] = __builtin_amdgcn_mfma_f32_16x16x32_bf16(
                        kf, qf[0][kb], sfT[0][bb], 0, 0, 0);
                    sfT[1][bb] = __builtin_amdgcn_mfma_f32_16x16x32_bf16(
                        kf, qf[1][kb], sfT[1][bb], 0, 0, 0);
                }
            }

            // ---- prefetch V fragments (independent of softmax; shared by i)
            // pair bp covers bb=2bp,2bp+1 -> keys bp*32+quad*4 and +16
            bf16x4 vlo[2][4], vhi[2][4];
            #pragma unroll
            for (int bp = 0; bp < 2; bp++)
                #pragma unroll
                for (int db = 0; db < 4; db++) {
                    const short* vb = &Vh[(size_t)(db * 16 + l16) * S_LEN
                                          + kbase + bp * 32 + quad * 4];
                    vlo[bp][db] = *(const bf16x4*)vb;
                    vhi[bp][db] = *(const bf16x4*)(vb + 16);
                }

            #pragma unroll
            for (int i = 0; i < 2; i++) {
                if (i == 0 && !a0) continue;                  // wave-uniform
                const int qg = qw0 + i * 16 + l16;
                if (maskn) {
                    #pragma unroll
                    for (int bb = 0; bb < 4; bb++)
                        #pragma unroll
                        for (int r = 0; r < 4; r++)
                            if (kbase + bb * 16 + quad * 4 + r > qg)
                                sfT[i][bb][r] = NEG_BIG;
                }
                float mx = sfT[i][0][0];
                #pragma unroll
                for (int bb = 0; bb < 4; bb++)
                    #pragma unroll
                    for (int r = 0; r < 4; r++) mx = fmaxf(mx, sfT[i][bb][r]);
                mx = fmaxf(mx, __shfl_xor(mx, 16, 64));
                mx = fmaxf(mx, __shfl_xor(mx, 32, 64));
                const float mnew = fmaxf(m_i[i], mx);
                const float alpha = EXP2F(m_i[i] - mnew);     // log2-domain
                m_i[i] = mnew;
                float rs = 0.f;
                #pragma unroll
                for (int bb = 0; bb < 4; bb++)
                    #pragma unroll
                    for (int r = 0; r < 4; r++) {
                        const float p = EXP2F(sfT[i][bb][r] - mnew);
                        sfT[i][bb][r] = p;
                        rs += p;
                    }
                rs += __shfl_xor(rs, 16, 64);
                rs += __shfl_xor(rs, 32, 64);
                l_i[i] = l_i[i] * alpha + rs;
                #pragma unroll
                for (int db = 0; db < 4; db++) o_acc[i][db] *= alpha;

                // ---- PV: full-K=32 MFMA, two bb sub-blocks per instruction
                #pragma unroll
                for (int bp = 0; bp < 2; bp++) {
                    int4 pv;
                    pv.x = (int)pack_bf16_rh(sfT[i][2 * bp][0],     sfT[i][2 * bp][1]);
                    pv.y = (int)pack_bf16_rh(sfT[i][2 * bp][2],     sfT[i][2 * bp][3]);
                    pv.z = (int)pack_bf16_rh(sfT[i][2 * bp + 1][0], sfT[i][2 * bp + 1][1]);
                    pv.w = (int)pack_bf16_rh(sfT[i][2 * bp + 1][2], sfT[i][2 * bp + 1][3]);
                    const bf16x8 pf = __builtin_bit_cast(bf16x8, pv);
                    #pragma unroll
                    for (int db = 0; db < 4; db++) {
                        const int2 lo2 = __builtin_bit_cast(int2, vlo[bp][db]);
                        const int2 hi2 = __builtin_bit_cast(int2, vhi[bp][db]);
                        int4 vi;
                        vi.x = lo2.x; vi.y = lo2.y; vi.z = hi2.x; vi.w = hi2.y;
                        const bf16x8 vf = __builtin_bit_cast(bf16x8, vi);
                        o_acc[i][db] = __builtin_amdgcn_mfma_f32_16x16x32_bf16(
                            vf, pf, o_acc[i][db], 0, 0, 0);
                    }
                }
            }
        }
    }

    const size_t slab = ((size_t)h * NCHUNK + kc) * S_LEN;
    #pragma unroll
    for (int i = 0; i < 2; i++) {
        const int q = qw0 + i * 16 + l16;
        if (quad == 0) {
            Mpart[slab + q] = m_i[i];
            Lpart[slab + q] = l_i[i];
        }
        #pragma unroll
        for (int db = 0; db < 4; db++) {
            short4 pk4;
            pk4.x = f2bf(o_acc[i][db][0]); pk4.y = f2bf(o_acc[i][db][1]);
            pk4.z = f2bf(o_acc[i][db][2]); pk4.w = f2bf(o_acc[i][db][3]);
            *(short4*)&Opart[(slab + q) * DH + db * 16 + quad * 4] = pk4;
        }
    }
}

// ---------------------------------------------------------------------------
// Kernel 2b: merge split-K partials -> Ctx bf16 [s][E]. (exp2-domain)
// ---------------------------------------------------------------------------
__global__ __launch_bounds__(256) void flash_merge(
    const short* __restrict__ Opart, const float* __restrict__ Mpart,
    const float* __restrict__ Lpart, short* __restrict__ Ctx)
{
    const int row = blockIdx.x * 4 + (threadIdx.x >> 6);
    const int lane = threadIdx.x & 63;
    const int h = row >> 12, q = row & 4095;
    const int nc = (q >> CKL2) + 1;

    float mv[NCHUNK], lv[NCHUNK];
    float M = NEG_BIG;
    #pragma unroll
    for (int c = 0; c < NCHUNK; c++) {
        if (c < nc) {
            mv[c] = Mpart[((size_t)h * NCHUNK + c) * S_LEN + q];
            lv[c] = Lpart[((size_t)h * NCHUNK + c) * S_LEN + q];
            M = fmaxf(M, mv[c]);
        }
    }
    float L = 0.f, O = 0.f;
    #pragma unroll
    for (int c = 0; c < NCHUNK; c++) {
        if (c < nc) {
            const float w = EXP2F(mv[c] - M);
            L += w * lv[c];
            O += w * bf2f(Opart[(((size_t)h * NCHUNK + c) * S_LEN + q) * DH + lane]);
        }
    }
    const float inv = (L > 0.f) ? 1.0f / L : 0.f;
    Ctx[(size_t)q * EMB + h * DH + lane] = f2bf(O * inv);
}

// ---------------------------------------------------------------------------
// Fallback single-pass flash (exp2-domain, Q pre-scaled) if ws too small.
// ---------------------------------------------------------------------------
__global__ __launch_bounds__(256) void flash_attn(
    const short* __restrict__ Qw, const short* __restrict__ Kw,
    const short* __restrict__ Vt, short* __restrict__ Ctx)
{
    __shared__ __align__(16) short Ks[128 * 64];
    __shared__ __align__(16) short Vs[64 * 128];
    __shared__ __align__(16) short Ps[4][32 * 128];

    const int h  = blockIdx.y;
    const int qt = (gridDim.x - 1) - blockIdx.x;
    const int q0 = qt * 128;
    const int t = threadIdx.x;
    const int lane = t & 63, wave = t >> 6;
    const int quad = lane >> 4, l16 = lane & 15;
    const int qw0 = q0 + wave * 32;

    bf16x8 qf[2][2];
    #pragma unroll
    for (int i = 0; i < 2; i++)
        #pragma unroll
        for (int kb = 0; kb < 2; kb++)
            qf[i][kb] = *(const bf16x8*)
                &Qw[((size_t)h * S_LEN + qw0 + i * 16 + l16) * DH + kb * 32 + quad * 8];

    float m_i[2][4], l_i[2][4];
    f32x4 o_acc[2][4] = {};
    #pragma unroll
    for (int i = 0; i < 2; i++)
        #pragma unroll
        for (int r = 0; r < 4; r++) { m_i[i][r] = NEG_BIG; l_i[i][r] = 0.f; }

    for (int kt = 0; kt <= qt; kt++) {
        const int k0 = kt * 128;
        __syncthreads();
        for (int c = t; c < 1024; c += 256) {
            const int row = c >> 3, cc = (c & 7) * 8;
            *(bf16x8*)&Ks[row * 64 + cc] =
                *(const bf16x8*)&Kw[((size_t)h * S_LEN + k0 + row) * DH + cc];
        }
        for (int c = t; c < 1024; c += 256) {
            const int row = c >> 4, cc = (c & 15) * 8;
            *(bf16x8*)&Vs[row * 128 + cc] =
                *(const bf16x8*)&Vt[((size_t)h * DH + row) * S_LEN + k0 + cc];
        }
        __syncthreads();

        f32x4 sf[2][8] = {};
        #pragma unroll
        for (int j = 0; j < 8; j++) {
            #pragma unroll
            for (int kb = 0; kb < 2; kb++) {
                const bf16x8 kf = *(const bf16x8*)
                    &Ks[(j * 16 + l16) * 64 + kb * 32 + quad * 8];
                #pragma unroll
                for (int i = 0; i < 2; i++)
                    sf[i][j] = __builtin_amdgcn_mfma_f32_16x16x32_bf16(
                        qf[i][kb], kf, sf[i][j], 0, 0, 0);
            }
        }

        const bool diag = (kt == qt);
        #pragma unroll
        for (int i = 0; i < 2; i++) {
            if (diag) {
                const int qbase = qw0 + i * 16 + quad * 4;
                const int kbase = k0 + l16;
                #pragma unroll
                for (int j = 0; j < 8; j++)
                    #pragma unroll
                    for (int r = 0; r < 4; r++)
                        if (kbase + j * 16 > qbase + r) sf[i][j][r] = NEG_BIG;
            }
            #pragma unroll
            for (int r = 0; r < 4; r++) {
                float mx = sf[i][0][r];
                #pragma unroll
                for (int j = 1; j < 8; j++) mx = fmaxf(mx, sf[i][j][r]);
                #pragma unroll
                for (int off = 1; off < 16; off <<= 1)
                    mx = fmaxf(mx, __shfl_xor(mx, off, 64));
                const float mnew = fmaxf(m_i[i][r], mx);
                const float alpha = EXP2F(m_i[i][r] - mnew);
                m_i[i][r] = mnew;
                float rs = 0.f;
                #pragma unroll
                for (int j = 0; j < 8; j++) {
                    const float p = EXP2F(sf[i][j][r] - mnew);
                    sf[i][j][r] = p;
                    rs += p;
                }
                #pragma unroll
                for (int off = 1; off < 16; off <<= 1)
                    rs += __shfl_xor(rs, off, 64);
                l_i[i][r] = l_i[i][r] * alpha + rs;
                #pragma unroll
                for (int db = 0; db < 4; db++) o_acc[i][db][r] *= alpha;
            }
            #pragma unroll
            for (int j = 0; j < 8; j++)
                #pragma unroll
                for (int r = 0; r < 4; r++)
                    Ps[wave][(i * 16 + quad * 4 + r) * 128 + j * 16 + l16] =
                        f2bf(sf[i][j][r]);
        }

        #pragma unroll
        for (int kb = 0; kb < 4; kb++) {
            bf16x8 pf[2];
            #pragma unroll
            for (int i = 0; i < 2; i++)
                pf[i] = *(const bf16x8*)
                    &Ps[wave][(i * 16 + l16) * 128 + kb * 32 + quad * 8];
            #pragma unroll
            for (int db = 0; db < 4; db++) {
                const bf16x8 vf = *(const bf16x8*)
                    &Vs[(db * 16 + l16) * 128 + kb * 32 + quad * 8];
                #pragma unroll
                for (int i = 0; i < 2; i++)
                    o_acc[i][db] = __builtin_amdgcn_mfma_f32_16x16x32_bf16(
                        pf[i], vf, o_acc[i][db], 0, 0, 0);
            }
        }
    }

    #pragma unroll
    for (int i = 0; i < 2; i++)
        #pragma unroll
        for (int r = 0; r < 4; r++) {
            const float li = l_i[i][r];
            const float inv = (li > 0.f) ? 1.0f / li : 0.f;
            const int m = qw0 + i * 16 + quad * 4 + r;
            #pragma unroll
            for (int db = 0; db < 4; db++) {
                const int d = db * 16 + l16;
                Ctx[(size_t)m * EMB + h * DH + d] = f2bf(o_acc[i][db][r] * inv);
            }
        }
}

// ---------------------------------------------------------------------------
// Kernel 3: output projection, bf16 inputs, global_load_lds staging.
// ---------------------------------------------------------------------------
__global__ __launch_bounds__(256) void out_gemm(
    const short* __restrict__ A, const short* __restrict__ Wb,
    const float* __restrict__ Bias, float* __restrict__ Out)
{
    __shared__ __align__(16) short As[128 * 64];
    __shared__ __align__(16) short Bs[128 * 64];

    const int m0 = blockIdx.x * 128;
    const int n0 = blockIdx.y * 128;
    const int t = threadIdx.x;
    const int lane = t & 63, wave = t >> 6;
    const int quad = lane >> 4, l16 = lane & 15;
    const int wm = (wave >> 1) * 64, wn = (wave & 1) * 64;
    const int srow = lane >> 3, scol = (lane & 7) * 8;

    f32x4 acc[4][4] = {};

    for (int k0 = 0; k0 < EMB; k0 += 64) {
        #pragma unroll
        for (int qd = 0; qd < 4; qd++) {
            const int chunk = wave * 4 + qd;
            const int row = chunk * 8 + srow;
            gld_lds16(&A [(size_t)(m0 + row) * EMB + k0 + scol], &As[chunk * 512]);
            gld_lds16(&Wb[(size_t)(n0 + row) * EMB + k0 + scol], &Bs[chunk * 512]);
        }
        __syncthreads();

        #pragma unroll
        for (int kb = 0; kb < 2; kb++) {
            bf16x8 af[4], bfr[4];
            #pragma unroll
            for (int i = 0; i < 4; i++)
                af[i] = *(const bf16x8*)&As[(wm + i * 16 + l16) * 64 + kb * 32 + quad * 8];
            #pragma unroll
            for (int j = 0; j < 4; j++)
                bfr[j] = *(const bf16x8*)&Bs[(wn + j * 16 + l16) * 64 + kb * 32 + quad * 8];
            #pragma unroll
            for (int i = 0; i < 4; i++)
                #pragma unroll
                for (int j = 0; j < 4; j++)
                    acc[i][j] = __builtin_amdgcn_mfma_f32_16x16x32_bf16(
                        af[i], bfr[j], acc[i][j], 0, 0, 0);
        }
        __syncthreads();
    }

    #pragma unroll
    for (int j = 0; j < 4; j++) {
        const int n = n0 + wn + j * 16 + l16;
        const float bias = Bias[n];
        #pragma unroll
        for (int i = 0; i < 4; i++)
            #pragma unroll
            for (int r = 0; r < 4; r++) {
                const int m = m0 + wm + i * 16 + quad * 4 + r;
                Out[(size_t)m * EMB + n] = acc[i][j][r] + bias;
            }
    }
}

// ---------------------------------------------------------------------------
extern "C" void kernel_launch(void* const* d_in, const int* in_sizes, int n_in,
                              void* d_out, int out_size, void* d_ws, size_t ws_size,
                              hipStream_t stream)
{
    (void)in_sizes; (void)n_in; (void)out_size;
    const float* x     = (const float*)d_in[0];
    const float* w_qkv = (const float*)d_in[2];
    const float* b_qkv = (const float*)d_in[3];
    const float* w_out = (const float*)d_in[4];
    const float* b_out = (const float*)d_in[5];
    float* out = (float*)d_out;

    char* ws = (char*)d_ws;
    const size_t SEG = (size_t)NH * S_LEN * DH * sizeof(short);     // 6 MB
    short* Qw  = (short*)(ws);
    short* Kw  = (short*)(ws + SEG);
    short* Vt  = (short*)(ws + 2 * SEG);
    short* Ctx = (short*)(ws + 3 * SEG);
    const size_t OP_OFF = 4 * SEG;
    const size_t OP_SZ  = (size_t)NH * NCHUNK * S_LEN * DH * sizeof(short);
    const size_t ML_SZ  = (size_t)NH * NCHUNK * S_LEN * sizeof(float);
    short* Opart = (short*)(ws + OP_OFF);
    float* Mpart = (float*)(ws + OP_OFF + OP_SZ);
    float* Lpart = (float*)(ws + OP_OFF + OP_SZ + ML_SZ);
    const size_t need = OP_OFF + OP_SZ + 2 * ML_SZ;

    const int XN8 = (S_LEN * EMB) / 8;
    const int WQ8 = (3 * EMB * EMB) / 8;
    const int WO8 = (EMB * EMB) / 8;
    const size_t WO_BYTES = (size_t)EMB * EMB * sizeof(short);
    short* Xb    = (short*)(ws + OP_OFF);
    short* Wqkvb = (short*)(ws + OP_OFF + (size_t)XN8 * 8 * sizeof(short));
    const bool big = ws_size >= need + WO_BYTES;
    short* Woutb = big ? (short*)(ws + need) : (short*)(ws + OP_OFF);

    if (big) {
        const int tot8 = XN8 + WQ8 + WO8;
        cvt3_bf16<<<dim3((tot8 + 255) / 256), 256, 0, stream>>>(
            x, Xb, XN8, w_qkv, Wqkvb, WQ8, w_out, Woutb, WO8);
    } else {
        cvt_bf16<<<dim3((XN8 + 255) / 256), 256, 0, stream>>>(x, Xb, XN8);
        cvt_bf16<<<dim3((WQ8 + 255) / 256), 256, 0, stream>>>(w_qkv, Wqkvb, WQ8);
    }

    qkv_gemm<<<dim3(S_LEN / 128, (3 * EMB) / 128), 256, 0, stream>>>(
        Xb, Wqkvb, b_qkv, Qw, Kw, Vt);

    if (ws_size >= need) {
        flash_partial<<<dim3(S_LEN / 64, NH, NCHUNK), 128, 0, stream>>>(
            Qw, Kw, Vt, Opart, Mpart, Lpart);
        flash_merge<<<dim3(NH * S_LEN / 4), 256, 0, stream>>>(
            Opart, Mpart, Lpart, Ctx);
    } else {
        flash_attn<<<dim3(S_LEN / 128, NH), 256, 0, stream>>>(Qw, Kw, Vt, Ctx);
    }

    if (!big)
        cvt_bf16<<<dim3((WO8 + 255) / 256), 256, 0, stream>>>(w_out, Woutb, WO8);
    out_gemm<<<dim3(S_LEN / 128, EMB / 128), 256, 0, stream>>>(
        Ctx, Woutb, b_out, out);
}

// Round 2
// 353.941 us; speedup vs baseline: 1.1993x; 1.1993x over previous
//
#include <hip/hip_runtime.h>
#include <hip/hip_bf16.h>

#define S_LEN 4096
#define EMB   768
#define NH    12
#define DH    64
#define NCHUNK 4
#define CKL2   10         // chunk keys = 1024

#define LOG2E 1.44269504088896f

// finite sentinel instead of -INFINITY: safe under fast-math builds
#define NEG_BIG (-1e30f)

// HW 2^x (v_exp_f32); __exp2f does not exist in HIP device code
#define EXP2F(x) __builtin_amdgcn_exp2f(x)

using bf16x8 = __attribute__((ext_vector_type(8))) short;
using bf16x4 = __attribute__((ext_vector_type(4))) short;
using f32x4  = __attribute__((ext_vector_type(4))) float;

__device__ __forceinline__ short f2bf(float f) {
    __hip_bfloat16 h = __float2bfloat16(f);
    short s; __builtin_memcpy(&s, &h, 2); return s;
}
__device__ __forceinline__ float bf2f(short s) {
    __hip_bfloat16 h; __builtin_memcpy(&h, &s, 2);
    return __bfloat162float(h);
}

// pack two f32 -> two bf16 (round-half-up) in one u32 via v_perm_b32
__device__ __forceinline__ unsigned pack_bf16_rh(float a, float b) {
    unsigned ua, ub;
    __builtin_memcpy(&ua, &a, 4);
    __builtin_memcpy(&ub, &b, 4);
    return __builtin_amdgcn_perm(ub + 0x8000u, ua + 0x8000u, 0x07060302u);
}

// async global->LDS, 16B per lane; lds dest = uniform base + lane*16
__device__ __forceinline__ void gld_lds16(const void* g, void* l) {
    __builtin_amdgcn_global_load_lds(
        (const __attribute__((address_space(1))) unsigned int*)g,
        (__attribute__((address_space(3))) unsigned int*)l, 16, 0, 0);
}

__device__ __forceinline__ void cvt8(const float* s, short* d, int i) {
    const float4 a = ((const float4*)s)[i * 2];
    const float4 b = ((const float4*)s)[i * 2 + 1];
    bf16x8 o;
    o[0] = f2bf(a.x); o[1] = f2bf(a.y); o[2] = f2bf(a.z); o[3] = f2bf(a.w);
    o[4] = f2bf(b.x); o[5] = f2bf(b.y); o[6] = f2bf(b.z); o[7] = f2bf(b.w);
    ((bf16x8*)d)[i] = o;
}

// ---------------------------------------------------------------------------
// Kernel 0a/0b: fp32 -> bf16 converts
// ---------------------------------------------------------------------------
__global__ __launch_bounds__(256) void cvt_bf16(
    const float* __restrict__ s, short* __restrict__ d, int n8)
{
    const int i = blockIdx.x * 256 + threadIdx.x;
    if (i < n8) cvt8(s, d, i);
}

__global__ __launch_bounds__(256) void cvt3_bf16(
    const float* __restrict__ x,  short* __restrict__ xb,  int n8x,
    const float* __restrict__ wq, short* __restrict__ wqb, int n8q,
    const float* __restrict__ wo, short* __restrict__ wob, int n8o)
{
    int i = blockIdx.x * 256 + threadIdx.x;
    if (i < n8x) { cvt8(x, xb, i); return; }
    i -= n8x;
    if (i < n8q) { cvt8(wq, wqb, i); return; }
    i -= n8q;
    if (i < n8o) cvt8(wo, wob, i);
}

// ---------------------------------------------------------------------------
// Kernel 1: QKV projection, bf16 inputs, global_load_lds staging.
// V-part tiles transpose C through LDS -> fully COALESCED Vt writes.
// Q pre-scaled by log2(e) so flash uses exp2 (1 instr).
// ---------------------------------------------------------------------------
__global__ __launch_bounds__(256) void qkv_gemm(
    const short* __restrict__ Xb, const short* __restrict__ Wb,
    const float* __restrict__ Bias,
    short* __restrict__ Qw, short* __restrict__ Kw, short* __restrict__ Vt)
{
    __shared__ __align__(16) short SMEM[2 * 128 * 64];  // As | Bs ; reused as T
    short* As = SMEM;
    short* Bs = SMEM + 128 * 64;

    const int m0 = blockIdx.x * 128;
    const int n0 = blockIdx.y * 128;
    const int t = threadIdx.x;
    const int lane = t & 63, wave = t >> 6;
    const int quad = lane >> 4, l16 = lane & 15;
    const int wm = (wave >> 1) * 64, wn = (wave & 1) * 64;
    const int srow = lane >> 3, scol = (lane & 7) * 8;

    f32x4 acc[4][4] = {};

    for (int k0 = 0; k0 < EMB; k0 += 64) {
        #pragma unroll
        for (int qd = 0; qd < 4; qd++) {
            const int chunk = wave * 4 + qd;
            const int row = chunk * 8 + srow;
            gld_lds16(&Xb[(size_t)(m0 + row) * EMB + k0 + scol], &As[chunk * 512]);
            gld_lds16(&Wb[(size_t)(n0 + row) * EMB + k0 + scol], &Bs[chunk * 512]);
        }
        __syncthreads();

        #pragma unroll
        for (int kb = 0; kb < 2; kb++) {
            bf16x8 af[4], bfr[4];
            #pragma unroll
            for (int i = 0; i < 4; i++)
                af[i] = *(const bf16x8*)&As[(wm + i * 16 + l16) * 64 + kb * 32 + quad * 8];
            #pragma unroll
            for (int j = 0; j < 4; j++)
                bfr[j] = *(const bf16x8*)&Bs[(wn + j * 16 + l16) * 64 + kb * 32 + quad * 8];
            #pragma unroll
            for (int i = 0; i < 4; i++)
                #pragma unroll
                for (int j = 0; j < 4; j++)
                    acc[i][j] = __builtin_amdgcn_mfma_f32_16x16x32_bf16(
                        af[i], bfr[j], acc[i][j], 0, 0, 0);
        }
        __syncthreads();
    }

    const int part = n0 / EMB;           // block-uniform: 0=Q 1=K 2=V

    if (part < 2) {
        // Q/K: Q scaled by log2e for exp2-domain softmax.
        const float qs = (part == 0) ? LOG2E : 1.0f;
        #pragma unroll
        for (int j = 0; j < 4; j++) {
            const int n = n0 + wn + j * 16 + l16;
            const float bias = Bias[n];
            const int r768 = n % EMB;
            const int h = r768 >> 6, d = r768 & 63;
            short* dst = (part == 0) ? Qw : Kw;
            #pragma unroll
            for (int i = 0; i < 4; i++)
                #pragma unroll
                for (int r = 0; r < 4; r++) {
                    const int m = m0 + wm + i * 16 + quad * 4 + r;
                    dst[((size_t)h * S_LEN + m) * DH + d] =
                        f2bf((acc[i][j][r] + bias) * qs);
                }
        }
    } else {
        // V: transpose C-tile through LDS T[128 n][128 m], coalesced Vt rows.
        #pragma unroll
        for (int j = 0; j < 4; j++) {
            const int nl = wn + j * 16 + l16;
            const float bias = Bias[n0 + nl];
            #pragma unroll
            for (int i = 0; i < 4; i++) {
                short4 v;
                v.x = f2bf(acc[i][j][0] + bias);
                v.y = f2bf(acc[i][j][1] + bias);
                v.z = f2bf(acc[i][j][2] + bias);
                v.w = f2bf(acc[i][j][3] + bias);
                *(short4*)&SMEM[nl * 128 + wm + i * 16 + quad * 4] = v;
            }
        }
        __syncthreads();
        const int vrow0 = n0 - 2 * EMB;          // Vt row base = h*64+d = r768
        #pragma unroll
        for (int c = t; c < 2048; c += 256) {    // 2048 chunks = 128 rows x 128 m
            const int row = c >> 4, off = (c & 15) * 8;
            *(bf16x8*)&Vt[(size_t)(vrow0 + row) * S_LEN + m0 + off] =
                *(const bf16x8*)&SMEM[row * 128 + off];
        }
    }
}

// ---------------------------------------------------------------------------
// Kernel 2a: split-K flash partial — staged-LDS v3.
// Post-mortem r1: LDS-free was latency-bound (MfmaUtil 4%, Occ 11%). Back to
// the proven 4-wave staged structure (113.7us) with targeted fixes:
//   * XOR swizzle byte^=((row&7)<<4) on K[128][64] and V[64][128] tiles,
//     applied on BOTH ds_write and ds_read (kills the 9.77M conflict cycles
//     the +pad layout left behind).
//   * Full-K=32 PV MFMA (PV count halves; 48 -> 32 MFMA/wave/k-tile).
//   * T14 async-STAGE: global->reg issue for tile kt+1 right after the
//     ds_writes of tile kt, RAW s_barrier (no vmcnt drain) so loads stay in
//     flight under a full tile of compute.
//   * T13 defer-max (THR=8, log2 domain): skip O-rescale when max growth
//     is small; P <= 2^8, f32 accum has headroom; merge math unaffected.
// ---------------------------------------------------------------------------
__global__ __launch_bounds__(256) void flash_partial(
    const short* __restrict__ Qw, const short* __restrict__ Kw,
    const short* __restrict__ Vt,
    short* __restrict__ Opart, float* __restrict__ Mpart,
    float* __restrict__ Lpart)
{
    const int qt = (gridDim.x - 1) - blockIdx.x;   // heavy-first
    const int h  = blockIdx.y;
    const int kc = blockIdx.z;
    const int q0  = qt * 64;
    const int ks0 = kc << CKL2;
    if (ks0 > q0) return;
    const int KIT = (1 << CKL2) / 128;   // 8
    const int T  = q0 >> 7;
    const int nk = min(KIT, T - KIT * kc + 1);

    // K tile [128 keys][64 d] | V tile [64 d][128 keys]; 16B-slot XOR swizzle
    __shared__ __align__(16) short SMEM[128 * 64 + 64 * 128];   // 32 KB
    short* Ks = SMEM;
    short* Vs = SMEM + 128 * 64;

    const int t = threadIdx.x;
    const int lane = t & 63, wave = t >> 6;
    const int quad = lane >> 4, l16 = lane & 15;
    const int qw0 = q0 + wave * 16;          // this wave's 16 q rows
    const int sw  = (l16 & 7) << 4;          // read-side swizzle mask (bytes)

    const short* Kh = Kw + (size_t)h * S_LEN * DH;
    const short* Vh = Vt + (size_t)h * DH * S_LEN;

    bf16x8 qf[2];
    #pragma unroll
    for (int kb = 0; kb < 2; kb++)
        qf[kb] = *(const bf16x8*)
            &Qw[((size_t)h * S_LEN + qw0 + l16) * DH + kb * 32 + quad * 8];

    float m_i = NEG_BIG, l_i = 0.f;
    f32x4 o_acc[4] = {};

    // staging registers: 4x16B K + 4x16B V per thread per tile
    int4 kst[4], vst[4];
    auto stage_issue = [&](int K0) {
        #pragma unroll
        for (int i = 0; i < 4; i++) {
            const int c = t + 256 * i;
            kst[i] = *(const int4*)&Kh[(size_t)(K0 + (c >> 3)) * DH + (c & 7) * 8];
            vst[i] = *(const int4*)&Vh[(size_t)(c >> 4) * S_LEN + K0 + (c & 15) * 8];
        }
    };

    stage_issue(ks0);

    for (int kt = 0; kt < nk; kt++) {
        const int k0 = ks0 + kt * 128;

        if (kt > 0) {                         // prev tile's LDS readers done
            asm volatile("" ::: "memory");
            __builtin_amdgcn_s_barrier();
            asm volatile("" ::: "memory");
        }
        // write staged regs -> LDS (swizzled); compiler inserts vmcnt waits
        #pragma unroll
        for (int i = 0; i < 4; i++) {
            const int c = t + 256 * i;
            const int rk = c >> 3;
            *(int4*)((char*)Ks + rk * 128 + (((c & 7) * 16) ^ ((rk & 7) << 4))) = kst[i];
            const int rv = c >> 4;
            *(int4*)((char*)Vs + rv * 256 + (((c & 15) * 16) ^ ((rv & 7) << 4))) = vst[i];
        }
        if (kt + 1 < nk) stage_issue(k0 + 128);   // in flight across barrier
        asm volatile("s_waitcnt lgkmcnt(0)" ::: "memory");
        __builtin_amdgcn_s_barrier();             // raw: no vmcnt drain
        asm volatile("" ::: "memory");

        const bool maskn = (k0 + 127 > q0);
        #pragma unroll
        for (int sub = 0; sub < 2; sub++) {
            const int kbase = k0 + sub * 64;
            if (maskn && kbase > qw0 + 15) continue;

            // ---- QK^T: sfT[bb][r] = score(key=kbase+bb*16+quad*4+r, q=qw0+l16)
            f32x4 sfT[4] = {};
            __builtin_amdgcn_s_setprio(1);
            #pragma unroll
            for (int bb = 0; bb < 4; bb++) {
                const int row = (sub * 4 + bb) * 16 + l16;
                #pragma unroll
                for (int kb = 0; kb < 2; kb++) {
                    const bf16x8 kf = *(const bf16x8*)((const char*)Ks
                        + row * 128 + ((kb * 64 + quad * 16) ^ sw));
                    sfT[bb] = __builtin_amdgcn_mfma_f32_16x16x32_bf16(
                        kf, qf[kb], sfT[bb], 0, 0, 0);
                }
            }
            __builtin_amdgcn_s_setprio(0);

            const int qg = qw0 + l16;
            if (maskn) {
                #pragma unroll
                for (int bb = 0; bb < 4; bb++)
                    #pragma unroll
                    for (int r = 0; r < 4; r++)
                        if (kbase + bb * 16 + quad * 4 + r > qg)
                            sfT[bb][r] = NEG_BIG;
            }

            // ---- online softmax, defer-max (T13)
            float mx = sfT[0][0];
            #pragma unroll
            for (int bb = 0; bb < 4; bb++)
                #pragma unroll
                for (int r = 0; r < 4; r++) mx = fmaxf(mx, sfT[bb][r]);
            mx = fmaxf(mx, __shfl_xor(mx, 16, 64));
            mx = fmaxf(mx, __shfl_xor(mx, 32, 64));
            if (!__all(mx <= m_i + 8.0f)) {
                const float mnew = fmaxf(m_i, mx);
                const float alpha = EXP2F(m_i - mnew);
                m_i = mnew;
                l_i *= alpha;
                #pragma unroll
                for (int db = 0; db < 4; db++) o_acc[db] *= alpha;
            }
            float rs = 0.f;
            #pragma unroll
            for (int bb = 0; bb < 4; bb++)
                #pragma unroll
                for (int r = 0; r < 4; r++) {
                    const float p = EXP2F(sfT[bb][r] - m_i);
                    sfT[bb][r] = p;
                    rs += p;
                }
            rs += __shfl_xor(rs, 16, 64);
            rs += __shfl_xor(rs, 32, 64);
            l_i += rs;

            // ---- PV: full-K=32 MFMA, two 16-key sub-blocks per instruction
            __builtin_amdgcn_s_setprio(1);
            #pragma unroll
            for (int bp = 0; bp < 2; bp++) {
                int4 pv;
                pv.x = (int)pack_bf16_rh(sfT[2 * bp][0],     sfT[2 * bp][1]);
                pv.y = (int)pack_bf16_rh(sfT[2 * bp][2],     sfT[2 * bp][3]);
                pv.z = (int)pack_bf16_rh(sfT[2 * bp + 1][0], sfT[2 * bp + 1][1]);
                pv.w = (int)pack_bf16_rh(sfT[2 * bp + 1][2], sfT[2 * bp + 1][3]);
                const bf16x8 pf = __builtin_bit_cast(bf16x8, pv);
                const int colb = (sub * 2 + bp) * 64 + quad * 8;  // lo byte col
                #pragma unroll
                for (int db = 0; db < 4; db++) {
                    const char* vb = (const char*)Vs + (db * 16 + l16) * 256;
                    const int2 lo2 = *(const int2*)(vb + (colb ^ sw));
                    const int2 hi2 = *(const int2*)(vb + ((colb + 32) ^ sw));
                    int4 vi; vi.x = lo2.x; vi.y = lo2.y; vi.z = hi2.x; vi.w = hi2.y;
                    o_acc[db] = __builtin_amdgcn_mfma_f32_16x16x32_bf16(
                        __builtin_bit_cast(bf16x8, vi), pf, o_acc[db], 0, 0, 0);
                }
            }
            __builtin_amdgcn_s_setprio(0);
        }
    }

    const size_t slab = ((size_t)h * NCHUNK + kc) * S_LEN;

    if (quad == 0) {
        const int q = qw0 + l16;
        Mpart[slab + q] = m_i;
        Lpart[slab + q] = l_i;
    }

    __syncthreads();
    #pragma unroll
    for (int db = 0; db < 4; db++) {
        short4 pk4;
        pk4.x = f2bf(o_acc[db][0]); pk4.y = f2bf(o_acc[db][1]);
        pk4.z = f2bf(o_acc[db][2]); pk4.w = f2bf(o_acc[db][3]);
        *(short4*)&SMEM[(wave * 16 + l16) * 72 + db * 16 + quad * 4] = pk4;
    }
    __syncthreads();
    #pragma unroll
    for (int c = t; c < 512; c += 256) {
        const int row = c >> 3, off = (c & 7) * 8;
        *(bf16x8*)&Opart[(slab + q0 + row) * DH + off] =
            *(const bf16x8*)&SMEM[row * 72 + off];
    }
}

// ---------------------------------------------------------------------------
// Kernel 2b: merge split-K partials -> Ctx bf16 [s][E]. (exp2-domain)
// ---------------------------------------------------------------------------
__global__ __launch_bounds__(256) void flash_merge(
    const short* __restrict__ Opart, const float* __restrict__ Mpart,
    const float* __restrict__ Lpart, short* __restrict__ Ctx)
{
    const int row = blockIdx.x * 4 + (threadIdx.x >> 6);
    const int lane = threadIdx.x & 63;
    const int h = row >> 12, q = row & 4095;
    const int nc = (q >> CKL2) + 1;

    float mv[NCHUNK], lv[NCHUNK];
    float M = NEG_BIG;
    #pragma unroll
    for (int c = 0; c < NCHUNK; c++) {
        if (c < nc) {
            mv[c] = Mpart[((size_t)h * NCHUNK + c) * S_LEN + q];
            lv[c] = Lpart[((size_t)h * NCHUNK + c) * S_LEN + q];
            M = fmaxf(M, mv[c]);
        }
    }
    float L = 0.f, O = 0.f;
    #pragma unroll
    for (int c = 0; c < NCHUNK; c++) {
        if (c < nc) {
            const float w = EXP2F(mv[c] - M);
            L += w * lv[c];
            O += w * bf2f(Opart[(((size_t)h * NCHUNK + c) * S_LEN + q) * DH + lane]);
        }
    }
    const float inv = (L > 0.f) ? 1.0f / L : 0.f;
    Ctx[(size_t)q * EMB + h * DH + lane] = f2bf(O * inv);
}

// ---------------------------------------------------------------------------
// Fallback single-pass flash (exp2-domain, Q pre-scaled) if ws too small.
// ---------------------------------------------------------------------------
__global__ __launch_bounds__(256) void flash_attn(
    const short* __restrict__ Qw, const short* __restrict__ Kw,
    const short* __restrict__ Vt, short* __restrict__ Ctx)
{
    __shared__ __align__(16) short Ks[128 * 64];
    __shared__ __align__(16) short Vs[64 * 128];
    __shared__ __align__(16) short Ps[4][32 * 128];

    const int h  = blockIdx.y;
    const int qt = (gridDim.x - 1) - blockIdx.x;
    const int q0 = qt * 128;
    const int t = threadIdx.x;
    const int lane = t & 63, wave = t >> 6;
    const int quad = lane >> 4, l16 = lane & 15;
    const int qw0 = q0 + wave * 32;

    bf16x8 qf[2][2];
    #pragma unroll
    for (int i = 0; i < 2; i++)
        #pragma unroll
        for (int kb = 0; kb < 2; kb++)
            qf[i][kb] = *(const bf16x8*)
                &Qw[((size_t)h * S_LEN + qw0 + i * 16 + l16) * DH + kb * 32 + quad * 8];

    float m_i[2][4], l_i[2][4];
    f32x4 o_acc[2][4] = {};
    #pragma unroll
    for (int i = 0; i < 2; i++)
        #pragma unroll
        for (int r = 0; r < 4; r++) { m_i[i][r] = NEG_BIG; l_i[i][r] = 0.f; }

    for (int kt = 0; kt <= qt; kt++) {
        const int k0 = kt * 128;
        __syncthreads();
        for (int c = t; c < 1024; c += 256) {
            const int row = c >> 3, cc = (c & 7) * 8;
            *(bf16x8*)&Ks[row * 64 + cc] =
                *(const bf16x8*)&Kw[((size_t)h * S_LEN + k0 + row) * DH + cc];
        }
        for (int c = t; c < 1024; c += 256) {
            const int row = c >> 4, cc = (c & 15) * 8;
            *(bf16x8*)&Vs[row * 128 + cc] =
                *(const bf16x8*)&Vt[((size_t)h * DH + row) * S_LEN + k0 + cc];
        }
        __syncthreads();

        f32x4 sf[2][8] = {};
        #pragma unroll
        for (int j = 0; j < 8; j++) {
            #pragma unroll
            for (int kb = 0; kb < 2; kb++) {
                const bf16x8 kf = *(const bf16x8*)
                    &Ks[(j * 16 + l16) * 64 + kb * 32 + quad * 8];
                #pragma unroll
                for (int i = 0; i < 2; i++)
                    sf[i][j] = __builtin_amdgcn_mfma_f32_16x16x32_bf16(
                        qf[i][kb], kf, sf[i][j], 0, 0, 0);
            }
        }

        const bool diag = (kt == qt);
        #pragma unroll
        for (int i = 0; i < 2; i++) {
            if (diag) {
                const int qbase = qw0 + i * 16 + quad * 4;
                const int kbase = k0 + l16;
                #pragma unroll
                for (int j = 0; j < 8; j++)
                    #pragma unroll
                    for (int r = 0; r < 4; r++)
                        if (kbase + j * 16 > qbase + r) sf[i][j][r] = NEG_BIG;
            }
            #pragma unroll
            for (int r = 0; r < 4; r++) {
                float mx = sf[i][0][r];
                #pragma unroll
                for (int j = 1; j < 8; j++) mx = fmaxf(mx, sf[i][j][r]);
                #pragma unroll
                for (int off = 1; off < 16; off <<= 1)
                    mx = fmaxf(mx, __shfl_xor(mx, off, 64));
                const float mnew = fmaxf(m_i[i][r], mx);
                const float alpha = EXP2F(m_i[i][r] - mnew);
                m_i[i][r] = mnew;
                float rs = 0.f;
                #pragma unroll
                for (int j = 0; j < 8; j++) {
                    const float p = EXP2F(sf[i][j][r] - mnew);
                    sf[i][j][r] = p;
                    rs += p;
                }
                #pragma unroll
                for (int off = 1; off < 16; off <<= 1)
                    rs += __shfl_xor(rs, off, 64);
                l_i[i][r] = l_i[i][r] * alpha + rs;
                #pragma unroll
                for (int db = 0; db < 4; db++) o_acc[i][db][r] *= alpha;
            }
            #pragma unroll
            for (int j = 0; j < 8; j++)
                #pragma unroll
                for (int r = 0; r < 4; r++)
                    Ps[wave][(i * 16 + quad * 4 + r) * 128 + j * 16 + l16] =
                        f2bf(sf[i][j][r]);
        }

        #pragma unroll
        for (int kb = 0; kb < 4; kb++) {
            bf16x8 pf[2];
            #pragma unroll
            for (int i = 0; i < 2; i++)
                pf[i] = *(const bf16x8*)
                    &Ps[wave][(i * 16 + l16) * 128 + kb * 32 + quad * 8];
            #pragma unroll
            for (int db = 0; db < 4; db++) {
                const bf16x8 vf = *(const bf16x8*)
                    &Vs[(db * 16 + l16) * 128 + kb * 32 + quad * 8];
                #pragma unroll
                for (int i = 0; i < 2; i++)
                    o_acc[i][db] = __builtin_amdgcn_mfma_f32_16x16x32_bf16(
                        pf[i], vf, o_acc[i][db], 0, 0, 0);
            }
        }
    }

    #pragma unroll
    for (int i = 0; i < 2; i++)
        #pragma unroll
        for (int r = 0; r < 4; r++) {
            const float li = l_i[i][r];
            const float inv = (li > 0.f) ? 1.0f / li : 0.f;
            const int m = qw0 + i * 16 + quad * 4 + r;
            #pragma unroll
            for (int db = 0; db < 4; db++) {
                const int d = db * 16 + l16;
                Ctx[(size_t)m * EMB + h * DH + d] = f2bf(o_acc[i][db][r] * inv);
            }
        }
}

// ---------------------------------------------------------------------------
// Kernel 3: output projection, bf16 inputs, global_load_lds staging.
// ---------------------------------------------------------------------------
__global__ __launch_bounds__(256) void out_gemm(
    const short* __restrict__ A, const short* __restrict__ Wb,
    const float* __restrict__ Bias, float* __restrict__ Out)
{
    __shared__ __align__(16) short As[128 * 64];
    __shared__ __align__(16) short Bs[128 * 64];

    const int m0 = blockIdx.x * 128;
    const int n0 = blockIdx.y * 128;
    const int t = threadIdx.x;
    const int lane = t & 63, wave = t >> 6;
    const int quad = lane >> 4, l16 = lane & 15;
    const int wm = (wave >> 1) * 64, wn = (wave & 1) * 64;
    const int srow = lane >> 3, scol = (lane & 7) * 8;

    f32x4 acc[4][4] = {};

    for (int k0 = 0; k0 < EMB; k0 += 64) {
        #pragma unroll
        for (int qd = 0; qd < 4; qd++) {
            const int chunk = wave * 4 + qd;
            const int row = chunk * 8 + srow;
            gld_lds16(&A [(size_t)(m0 + row) * EMB + k0 + scol], &As[chunk * 512]);
            gld_lds16(&Wb[(size_t)(n0 + row) * EMB + k0 + scol], &Bs[chunk * 512]);
        }
        __syncthreads();

        #pragma unroll
        for (int kb = 0; kb < 2; kb++) {
            bf16x8 af[4], bfr[4];
            #pragma unroll
            for (int i = 0; i < 4; i++)
                af[i] = *(const bf16x8*)&As[(wm + i * 16 + l16) * 64 + kb * 32 + quad * 8];
            #pragma unroll
            for (int j = 0; j < 4; j++)
                bfr[j] = *(const bf16x8*)&Bs[(wn + j * 16 + l16) * 64 + kb * 32 + quad * 8];
            #pragma unroll
            for (int i = 0; i < 4; i++)
                #pragma unroll
                for (int j = 0; j < 4; j++)
                    acc[i][j] = __builtin_amdgcn_mfma_f32_16x16x32_bf16(
                        af[i], bfr[j], acc[i][j], 0, 0, 0);
        }
        __syncthreads();
    }

    #pragma unroll
    for (int j = 0; j < 4; j++) {
        const int n = n0 + wn + j * 16 + l16;
        const float bias = Bias[n];
        #pragma unroll
        for (int i = 0; i < 4; i++)
            #pragma unroll
            for (int r = 0; r < 4; r++) {
                const int m = m0 + wm + i * 16 + quad * 4 + r;
                Out[(size_t)m * EMB + n] = acc[i][j][r] + bias;
            }
    }
}

// ---------------------------------------------------------------------------
extern "C" void kernel_launch(void* const* d_in, const int* in_sizes, int n_in,
                              void* d_out, int out_size, void* d_ws, size_t ws_size,
                              hipStream_t stream)
{
    (void)in_sizes; (void)n_in; (void)out_size;
    const float* x     = (const float*)d_in[0];
    const float* w_qkv = (const float*)d_in[2];
    const float* b_qkv = (const float*)d_in[3];
    const float* w_out = (const float*)d_in[4];
    const float* b_out = (const float*)d_in[5];
    float* out = (float*)d_out;

    char* ws = (char*)d_ws;
    const size_t SEG = (size_t)NH * S_LEN * DH * sizeof(short);     // 6 MB
    short* Qw  = (short*)(ws);
    short* Kw  = (short*)(ws + SEG);
    short* Vt  = (short*)(ws + 2 * SEG);
    short* Ctx = (short*)(ws + 3 * SEG);
    const size_t OP_OFF = 4 * SEG;
    const size_t OP_SZ  = (size_t)NH * NCHUNK * S_LEN * DH * sizeof(short);
    const size_t ML_SZ  = (size_t)NH * NCHUNK * S_LEN * sizeof(float);
    short* Opart = (short*)(ws + OP_OFF);
    float* Mpart = (float*)(ws + OP_OFF + OP_SZ);
    float* Lpart = (float*)(ws + OP_OFF + OP_SZ + ML_SZ);
    const size_t need = OP_OFF + OP_SZ + 2 * ML_SZ;

    const int XN8 = (S_LEN * EMB) / 8;
    const int WQ8 = (3 * EMB * EMB) / 8;
    const int WO8 = (EMB * EMB) / 8;
    const size_t WO_BYTES = (size_t)EMB * EMB * sizeof(short);
    short* Xb    = (short*)(ws + OP_OFF);
    short* Wqkvb = (short*)(ws + OP_OFF + (size_t)XN8 * 8 * sizeof(short));
    const bool big = ws_size >= need + WO_BYTES;
    short* Woutb = big ? (short*)(ws + need) : (short*)(ws + OP_OFF);

    if (big) {
        const int tot8 = XN8 + WQ8 + WO8;
        cvt3_bf16<<<dim3((tot8 + 255) / 256), 256, 0, stream>>>(
            x, Xb, XN8, w_qkv, Wqkvb, WQ8, w_out, Woutb, WO8);
    } else {
        cvt_bf16<<<dim3((XN8 + 255) / 256), 256, 0, stream>>>(x, Xb, XN8);
        cvt_bf16<<<dim3((WQ8 + 255) / 256), 256, 0, stream>>>(w_qkv, Wqkvb, WQ8);
    }

    qkv_gemm<<<dim3(S_LEN / 128, (3 * EMB) / 128), 256, 0, stream>>>(
        Xb, Wqkvb, b_qkv, Qw, Kw, Vt);

    if (ws_size >= need) {
        flash_partial<<<dim3(S_LEN / 64, NH, NCHUNK), 256, 0, stream>>>(
            Qw, Kw, Vt, Opart, Mpart, Lpart);
        flash_merge<<<dim3(NH * S_LEN / 4), 256, 0, stream>>>(
            Opart, Mpart, Lpart, Ctx);
    } else {
        flash_attn<<<dim3(S_LEN / 128, NH), 256, 0, stream>>>(Qw, Kw, Vt, Ctx);
    }

    if (!big)
        cvt_bf16<<<dim3((WO8 + 255) / 256), 256, 0, stream>>>(w_out, Woutb, WO8);
    out_gemm<<<dim3(S_LEN / 128, EMB / 128), 256, 0, stream>>>(
        Ctx, Woutb, b_out, out);
}

// Round 3
// 254.355 us; speedup vs baseline: 1.6689x; 1.3915x over previous
//
#include <hip/hip_runtime.h>
#include <hip/hip_bf16.h>

#define S_LEN 4096
#define EMB   768
#define NH    12
#define DH    64
#define NCHUNK 4
#define CKL2   10         // chunk keys = 1024

#define LOG2E 1.44269504088896f

// finite sentinel instead of -INFINITY: safe under fast-math builds
#define NEG_BIG (-1e30f)

// HW 2^x (v_exp_f32); __exp2f does not exist in HIP device code
#define EXP2F(x) __builtin_amdgcn_exp2f(x)

using bf16x8 = __attribute__((ext_vector_type(8))) short;
using bf16x4 = __attribute__((ext_vector_type(4))) short;
using f32x4  = __attribute__((ext_vector_type(4))) float;

__device__ __forceinline__ short f2bf(float f) {
    __hip_bfloat16 h = __float2bfloat16(f);
    short s; __builtin_memcpy(&s, &h, 2); return s;
}
__device__ __forceinline__ float bf2f(short s) {
    __hip_bfloat16 h; __builtin_memcpy(&h, &s, 2);
    return __bfloat162float(h);
}

// pack two f32 -> two bf16 (round-half-up) in one u32 via v_perm_b32
__device__ __forceinline__ unsigned pack_bf16_rh(float a, float b) {
    unsigned ua, ub;
    __builtin_memcpy(&ua, &a, 4);
    __builtin_memcpy(&ub, &b, 4);
    return __builtin_amdgcn_perm(ub + 0x8000u, ua + 0x8000u, 0x07060302u);
}

// async global->LDS, 16B per lane; lds dest = uniform base + lane*16
__device__ __forceinline__ void gld_lds16(const void* g, void* l) {
    __builtin_amdgcn_global_load_lds(
        (const __attribute__((address_space(1))) unsigned int*)g,
        (__attribute__((address_space(3))) unsigned int*)l, 16, 0, 0);
}

__device__ __forceinline__ void cvt8(const float* s, short* d, int i) {
    const float4 a = ((const float4*)s)[i * 2];
    const float4 b = ((const float4*)s)[i * 2 + 1];
    bf16x8 o;
    o[0] = f2bf(a.x); o[1] = f2bf(a.y); o[2] = f2bf(a.z); o[3] = f2bf(a.w);
    o[4] = f2bf(b.x); o[5] = f2bf(b.y); o[6] = f2bf(b.z); o[7] = f2bf(b.w);
    ((bf16x8*)d)[i] = o;
}

// ---------------------------------------------------------------------------
// Kernel 0a/0b: fp32 -> bf16 converts
// ---------------------------------------------------------------------------
__global__ __launch_bounds__(256) void cvt_bf16(
    const float* __restrict__ s, short* __restrict__ d, int n8)
{
    const int i = blockIdx.x * 256 + threadIdx.x;
    if (i < n8) cvt8(s, d, i);
}

__global__ __launch_bounds__(256) void cvt3_bf16(
    const float* __restrict__ x,  short* __restrict__ xb,  int n8x,
    const float* __restrict__ wq, short* __restrict__ wqb, int n8q,
    const float* __restrict__ wo, short* __restrict__ wob, int n8o)
{
    int i = blockIdx.x * 256 + threadIdx.x;
    if (i < n8x) { cvt8(x, xb, i); return; }
    i -= n8x;
    if (i < n8q) { cvt8(wq, wqb, i); return; }
    i -= n8q;
    if (i < n8o) cvt8(wo, wob, i);
}

// ---------------------------------------------------------------------------
// Kernel 1: QKV projection, bf16 inputs, global_load_lds staging.
// V-part tiles transpose C through LDS -> fully COALESCED Vt writes.
// Q pre-scaled by log2(e) so flash uses exp2 (1 instr).
// ---------------------------------------------------------------------------
__global__ __launch_bounds__(256) void qkv_gemm(
    const short* __restrict__ Xb, const short* __restrict__ Wb,
    const float* __restrict__ Bias,
    short* __restrict__ Qw, short* __restrict__ Kw, short* __restrict__ Vt)
{
    __shared__ __align__(16) short SMEM[2 * 128 * 64];  // As | Bs ; reused as T
    short* As = SMEM;
    short* Bs = SMEM + 128 * 64;

    const int m0 = blockIdx.x * 128;
    const int n0 = blockIdx.y * 128;
    const int t = threadIdx.x;
    const int lane = t & 63, wave = t >> 6;
    const int quad = lane >> 4, l16 = lane & 15;
    const int wm = (wave >> 1) * 64, wn = (wave & 1) * 64;
    const int srow = lane >> 3, scol = (lane & 7) * 8;

    f32x4 acc[4][4] = {};

    for (int k0 = 0; k0 < EMB; k0 += 64) {
        #pragma unroll
        for (int qd = 0; qd < 4; qd++) {
            const int chunk = wave * 4 + qd;
            const int row = chunk * 8 + srow;
            gld_lds16(&Xb[(size_t)(m0 + row) * EMB + k0 + scol], &As[chunk * 512]);
            gld_lds16(&Wb[(size_t)(n0 + row) * EMB + k0 + scol], &Bs[chunk * 512]);
        }
        __syncthreads();

        #pragma unroll
        for (int kb = 0; kb < 2; kb++) {
            bf16x8 af[4], bfr[4];
            #pragma unroll
            for (int i = 0; i < 4; i++)
                af[i] = *(const bf16x8*)&As[(wm + i * 16 + l16) * 64 + kb * 32 + quad * 8];
            #pragma unroll
            for (int j = 0; j < 4; j++)
                bfr[j] = *(const bf16x8*)&Bs[(wn + j * 16 + l16) * 64 + kb * 32 + quad * 8];
            #pragma unroll
            for (int i = 0; i < 4; i++)
                #pragma unroll
                for (int j = 0; j < 4; j++)
                    acc[i][j] = __builtin_amdgcn_mfma_f32_16x16x32_bf16(
                        af[i], bfr[j], acc[i][j], 0, 0, 0);
        }
        __syncthreads();
    }

    const int part = n0 / EMB;           // block-uniform: 0=Q 1=K 2=V

    if (part < 2) {
        // Q/K: Q scaled by log2e for exp2-domain softmax.
        const float qs = (part == 0) ? LOG2E : 1.0f;
        #pragma unroll
        for (int j = 0; j < 4; j++) {
            const int n = n0 + wn + j * 16 + l16;
            const float bias = Bias[n];
            const int r768 = n % EMB;
            const int h = r768 >> 6, d = r768 & 63;
            short* dst = (part == 0) ? Qw : Kw;
            #pragma unroll
            for (int i = 0; i < 4; i++)
                #pragma unroll
                for (int r = 0; r < 4; r++) {
                    const int m = m0 + wm + i * 16 + quad * 4 + r;
                    dst[((size_t)h * S_LEN + m) * DH + d] =
                        f2bf((acc[i][j][r] + bias) * qs);
                }
        }
    } else {
        // V: transpose C-tile through LDS T[128 n][128 m], coalesced Vt rows.
        #pragma unroll
        for (int j = 0; j < 4; j++) {
            const int nl = wn + j * 16 + l16;
            const float bias = Bias[n0 + nl];
            #pragma unroll
            for (int i = 0; i < 4; i++) {
                short4 v;
                v.x = f2bf(acc[i][j][0] + bias);
                v.y = f2bf(acc[i][j][1] + bias);
                v.z = f2bf(acc[i][j][2] + bias);
                v.w = f2bf(acc[i][j][3] + bias);
                *(short4*)&SMEM[nl * 128 + wm + i * 16 + quad * 4] = v;
            }
        }
        __syncthreads();
        const int vrow0 = n0 - 2 * EMB;          // Vt row base = h*64+d = r768
        #pragma unroll
        for (int c = t; c < 2048; c += 256) {    // 2048 chunks = 128 rows x 128 m
            const int row = c >> 4, off = (c & 15) * 8;
            *(bf16x8*)&Vt[(size_t)(vrow0 + row) * S_LEN + m0 + off] =
                *(const bf16x8*)&SMEM[row * 128 + off];
        }
    }
}

// ---------------------------------------------------------------------------
// Kernel 2a: split-K flash partial — v4.
// Post-mortem r2: reg-staging spilled (WRITE_SIZE 368MB = scratch; VGPR
// allocator stuck at 64). Fix: stage via global_load_lds with PRE-SWIZZLED
// GLOBAL SOURCE (rule #21/m173) -> swizzled LDS, zero staging VGPRs, async
// DMA. LDS dest stays linear (required by gld_lds); the source col slot is
// XORed with the row bits, and the read side applies the same XOR.
//   K tile [128 k][64 d] rows=128B, 8 slots:  src slot = sc ^ (rk&7)
//   V tile [64 d][128 k] rows=256B, 16 slots: src slot = sc ^ (rv&15)
//     -> V 8B PV reads become 2 lanes/bank (free, m136).
// Keep: full-K=32 PV, defer-max (T13), setprio, heavy-first, plain
// __syncthreads (drain hidden by 5 blocks/CU TLP, m114).
// __launch_bounds__(256,4): budget 128 VGPRs so the allocator never spills.
// ---------------------------------------------------------------------------
__global__ __launch_bounds__(256, 4) void flash_partial(
    const short* __restrict__ Qw, const short* __restrict__ Kw,
    const short* __restrict__ Vt,
    short* __restrict__ Opart, float* __restrict__ Mpart,
    float* __restrict__ Lpart)
{
    const int qt = (gridDim.x - 1) - blockIdx.x;   // heavy-first
    const int h  = blockIdx.y;
    const int kc = blockIdx.z;
    const int q0  = qt * 64;
    const int ks0 = kc << CKL2;
    if (ks0 > q0) return;
    const int KIT = (1 << CKL2) / 128;   // 8
    const int T  = q0 >> 7;
    const int nk = min(KIT, T - KIT * kc + 1);

    __shared__ __align__(16) short SMEM[128 * 64 + 64 * 128];   // 32 KB
    short* Ks = SMEM;
    short* Vs = SMEM + 128 * 64;

    const int t = threadIdx.x;
    const int lane = t & 63, wave = t >> 6;
    const int quad = lane >> 4, l16 = lane & 15;
    const int qw0 = q0 + wave * 16;          // this wave's 16 q rows
    const int swk = (l16 & 7) << 4;          // K read swizzle (bytes)
    const int swv = l16 << 4;                // V read swizzle (bytes, 4 bits)

    const short* Kh = Kw + (size_t)h * S_LEN * DH;
    const short* Vh = Vt + (size_t)h * DH * S_LEN;

    // staging geometry: 16 chunks of 1024B each for K and V; 4 chunks/wave.
    const int krow = lane >> 3;              // K: row-in-chunk 0..7
    const int kcol = ((lane & 7) ^ krow) << 3;   // pre-swizzled col (shorts)
    const int vrow = lane >> 4;              // V: row-in-chunk 0..3
    const int vsc  = lane & 15;              // 16B slot in 256B row

    bf16x8 qf[2];
    #pragma unroll
    for (int kb = 0; kb < 2; kb++)
        qf[kb] = *(const bf16x8*)
            &Qw[((size_t)h * S_LEN + qw0 + l16) * DH + kb * 32 + quad * 8];

    float m_i = NEG_BIG, l_i = 0.f;
    f32x4 o_acc[4] = {};

    for (int kt = 0; kt < nk; kt++) {
        const int k0 = ks0 + kt * 128;

        __syncthreads();                     // prev tile's readers done
        #pragma unroll
        for (int i = 0; i < 4; i++) {
            const int ck = wave * 4 + i;                 // chunk 0..15
            const int rk = ck * 8 + krow;                // K tile row (key)
            gld_lds16(&Kh[(size_t)(k0 + rk) * DH + kcol], &Ks[ck * 512]);
            const int rv = ck * 4 + vrow;                // V tile row (d)
            const int vcol = (vsc ^ (rv & 15)) << 3;
            gld_lds16(&Vh[(size_t)rv * S_LEN + k0 + vcol], &Vs[ck * 512]);
        }
        __syncthreads();                     // drains vmcnt: data landed

        const bool maskn = (k0 + 127 > q0);
        #pragma unroll
        for (int sub = 0; sub < 2; sub++) {
            const int kbase = k0 + sub * 64;
            if (maskn && kbase > qw0 + 15) continue;

            // ---- QK^T: sfT[bb][r] = score(key=kbase+bb*16+quad*4+r, q=qw0+l16)
            f32x4 sfT[4] = {};
            __builtin_amdgcn_s_setprio(1);
            #pragma unroll
            for (int bb = 0; bb < 4; bb++) {
                const int row = (sub * 4 + bb) * 16 + l16;
                #pragma unroll
                for (int kb = 0; kb < 2; kb++) {
                    const bf16x8 kf = *(const bf16x8*)((const char*)Ks
                        + row * 128 + ((kb * 64 + quad * 16) ^ swk));
                    sfT[bb] = __builtin_amdgcn_mfma_f32_16x16x32_bf16(
                        kf, qf[kb], sfT[bb], 0, 0, 0);
                }
            }
            __builtin_amdgcn_s_setprio(0);

            const int qg = qw0 + l16;
            if (maskn) {
                #pragma unroll
                for (int bb = 0; bb < 4; bb++)
                    #pragma unroll
                    for (int r = 0; r < 4; r++)
                        if (kbase + bb * 16 + quad * 4 + r > qg)
                            sfT[bb][r] = NEG_BIG;
            }

            // ---- online softmax, defer-max (T13, THR=8 in log2 domain)
            float mx = sfT[0][0];
            #pragma unroll
            for (int bb = 0; bb < 4; bb++)
                #pragma unroll
                for (int r = 0; r < 4; r++) mx = fmaxf(mx, sfT[bb][r]);
            mx = fmaxf(mx, __shfl_xor(mx, 16, 64));
            mx = fmaxf(mx, __shfl_xor(mx, 32, 64));
            if (!__all(mx <= m_i + 8.0f)) {
                const float mnew = fmaxf(m_i, mx);
                const float alpha = EXP2F(m_i - mnew);
                m_i = mnew;
                l_i *= alpha;
                #pragma unroll
                for (int db = 0; db < 4; db++) o_acc[db] *= alpha;
            }
            float rs = 0.f;
            #pragma unroll
            for (int bb = 0; bb < 4; bb++)
                #pragma unroll
                for (int r = 0; r < 4; r++) {
                    const float p = EXP2F(sfT[bb][r] - m_i);
                    sfT[bb][r] = p;
                    rs += p;
                }
            rs += __shfl_xor(rs, 16, 64);
            rs += __shfl_xor(rs, 32, 64);
            l_i += rs;

            // ---- PV: full-K=32 MFMA; permuted-K packing (same perm on A&B)
            __builtin_amdgcn_s_setprio(1);
            #pragma unroll
            for (int bp = 0; bp < 2; bp++) {
                int4 pv;
                pv.x = (int)pack_bf16_rh(sfT[2 * bp][0],     sfT[2 * bp][1]);
                pv.y = (int)pack_bf16_rh(sfT[2 * bp][2],     sfT[2 * bp][3]);
                pv.z = (int)pack_bf16_rh(sfT[2 * bp + 1][0], sfT[2 * bp + 1][1]);
                pv.w = (int)pack_bf16_rh(sfT[2 * bp + 1][2], sfT[2 * bp + 1][3]);
                const bf16x8 pf = __builtin_bit_cast(bf16x8, pv);
                const int colb = (sub * 2 + bp) * 64 + quad * 8;  // lo byte col
                #pragma unroll
                for (int db = 0; db < 4; db++) {
                    const char* vb = (const char*)Vs + (db * 16 + l16) * 256;
                    const int2 lo2 = *(const int2*)(vb + (colb ^ swv));
                    const int2 hi2 = *(const int2*)(vb + ((colb + 32) ^ swv));
                    int4 vi; vi.x = lo2.x; vi.y = lo2.y; vi.z = hi2.x; vi.w = hi2.y;
                    o_acc[db] = __builtin_amdgcn_mfma_f32_16x16x32_bf16(
                        __builtin_bit_cast(bf16x8, vi), pf, o_acc[db], 0, 0, 0);
                }
            }
            __builtin_amdgcn_s_setprio(0);
        }
    }

    const size_t slab = ((size_t)h * NCHUNK + kc) * S_LEN;

    if (quad == 0) {
        const int q = qw0 + l16;
        Mpart[slab + q] = m_i;
        Lpart[slab + q] = l_i;
    }

    __syncthreads();
    #pragma unroll
    for (int db = 0; db < 4; db++) {
        short4 pk4;
        pk4.x = f2bf(o_acc[db][0]); pk4.y = f2bf(o_acc[db][1]);
        pk4.z = f2bf(o_acc[db][2]); pk4.w = f2bf(o_acc[db][3]);
        *(short4*)&SMEM[(wave * 16 + l16) * 72 + db * 16 + quad * 4] = pk4;
    }
    __syncthreads();
    #pragma unroll
    for (int c = t; c < 512; c += 256) {
        const int row = c >> 3, off = (c & 7) * 8;
        *(bf16x8*)&Opart[(slab + q0 + row) * DH + off] =
            *(const bf16x8*)&SMEM[row * 72 + off];
    }
}

// ---------------------------------------------------------------------------
// Kernel 2b: merge split-K partials -> Ctx bf16 [s][E]. (exp2-domain)
// ---------------------------------------------------------------------------
__global__ __launch_bounds__(256) void flash_merge(
    const short* __restrict__ Opart, const float* __restrict__ Mpart,
    const float* __restrict__ Lpart, short* __restrict__ Ctx)
{
    const int row = blockIdx.x * 4 + (threadIdx.x >> 6);
    const int lane = threadIdx.x & 63;
    const int h = row >> 12, q = row & 4095;
    const int nc = (q >> CKL2) + 1;

    float mv[NCHUNK], lv[NCHUNK];
    float M = NEG_BIG;
    #pragma unroll
    for (int c = 0; c < NCHUNK; c++) {
        if (c < nc) {
            mv[c] = Mpart[((size_t)h * NCHUNK + c) * S_LEN + q];
            lv[c] = Lpart[((size_t)h * NCHUNK + c) * S_LEN + q];
            M = fmaxf(M, mv[c]);
        }
    }
    float L = 0.f, O = 0.f;
    #pragma unroll
    for (int c = 0; c < NCHUNK; c++) {
        if (c < nc) {
            const float w = EXP2F(mv[c] - M);
            L += w * lv[c];
            O += w * bf2f(Opart[(((size_t)h * NCHUNK + c) * S_LEN + q) * DH + lane]);
        }
    }
    const float inv = (L > 0.f) ? 1.0f / L : 0.f;
    Ctx[(size_t)q * EMB + h * DH + lane] = f2bf(O * inv);
}

// ---------------------------------------------------------------------------
// Fallback single-pass flash (exp2-domain, Q pre-scaled) if ws too small.
// ---------------------------------------------------------------------------
__global__ __launch_bounds__(256) void flash_attn(
    const short* __restrict__ Qw, const short* __restrict__ Kw,
    const short* __restrict__ Vt, short* __restrict__ Ctx)
{
    __shared__ __align__(16) short Ks[128 * 64];
    __shared__ __align__(16) short Vs[64 * 128];
    __shared__ __align__(16) short Ps[4][32 * 128];

    const int h  = blockIdx.y;
    const int qt = (gridDim.x - 1) - blockIdx.x;
    const int q0 = qt * 128;
    const int t = threadIdx.x;
    const int lane = t & 63, wave = t >> 6;
    const int quad = lane >> 4, l16 = lane & 15;
    const int qw0 = q0 + wave * 32;

    bf16x8 qf[2][2];
    #pragma unroll
    for (int i = 0; i < 2; i++)
        #pragma unroll
        for (int kb = 0; kb < 2; kb++)
            qf[i][kb] = *(const bf16x8*)
                &Qw[((size_t)h * S_LEN + qw0 + i * 16 + l16) * DH + kb * 32 + quad * 8];

    float m_i[2][4], l_i[2][4];
    f32x4 o_acc[2][4] = {};
    #pragma unroll
    for (int i = 0; i < 2; i++)
        #pragma unroll
        for (int r = 0; r < 4; r++) { m_i[i][r] = NEG_BIG; l_i[i][r] = 0.f; }

    for (int kt = 0; kt <= qt; kt++) {
        const int k0 = kt * 128;
        __syncthreads();
        for (int c = t; c < 1024; c += 256) {
            const int row = c >> 3, cc = (c & 7) * 8;
            *(bf16x8*)&Ks[row * 64 + cc] =
                *(const bf16x8*)&Kw[((size_t)h * S_LEN + k0 + row) * DH + cc];
        }
        for (int c = t; c < 1024; c += 256) {
            const int row = c >> 4, cc = (c & 15) * 8;
            *(bf16x8*)&Vs[row * 128 + cc] =
                *(const bf16x8*)&Vt[((size_t)h * DH + row) * S_LEN + k0 + cc];
        }
        __syncthreads();

        f32x4 sf[2][8] = {};
        #pragma unroll
        for (int j = 0; j < 8; j++) {
            #pragma unroll
            for (int kb = 0; kb < 2; kb++) {
                const bf16x8 kf = *(const bf16x8*)
                    &Ks[(j * 16 + l16) * 64 + kb * 32 + quad * 8];
                #pragma unroll
                for (int i = 0; i < 2; i++)
                    sf[i][j] = __builtin_amdgcn_mfma_f32_16x16x32_bf16(
                        qf[i][kb], kf, sf[i][j], 0, 0, 0);
            }
        }

        const bool diag = (kt == qt);
        #pragma unroll
        for (int i = 0; i < 2; i++) {
            if (diag) {
                const int qbase = qw0 + i * 16 + quad * 4;
                const int kbase = k0 + l16;
                #pragma unroll
                for (int j = 0; j < 8; j++)
                    #pragma unroll
                    for (int r = 0; r < 4; r++)
                        if (kbase + j * 16 > qbase + r) sf[i][j][r] = NEG_BIG;
            }
            #pragma unroll
            for (int r = 0; r < 4; r++) {
                float mx = sf[i][0][r];
                #pragma unroll
                for (int j = 1; j < 8; j++) mx = fmaxf(mx, sf[i][j][r]);
                #pragma unroll
                for (int off = 1; off < 16; off <<= 1)
                    mx = fmaxf(mx, __shfl_xor(mx, off, 64));
                const float mnew = fmaxf(m_i[i][r], mx);
                const float alpha = EXP2F(m_i[i][r] - mnew);
                m_i[i][r] = mnew;
                float rs = 0.f;
                #pragma unroll
                for (int j = 0; j < 8; j++) {
                    const float p = EXP2F(sf[i][j][r] - mnew);
                    sf[i][j][r] = p;
                    rs += p;
                }
                #pragma unroll
                for (int off = 1; off < 16; off <<= 1)
                    rs += __shfl_xor(rs, off, 64);
                l_i[i][r] = l_i[i][r] * alpha + rs;
                #pragma unroll
                for (int db = 0; db < 4; db++) o_acc[i][db][r] *= alpha;
            }
            #pragma unroll
            for (int j = 0; j < 8; j++)
                #pragma unroll
                for (int r = 0; r < 4; r++)
                    Ps[wave][(i * 16 + quad * 4 + r) * 128 + j * 16 + l16] =
                        f2bf(sf[i][j][r]);
        }

        #pragma unroll
        for (int kb = 0; kb < 4; kb++) {
            bf16x8 pf[2];
            #pragma unroll
            for (int i = 0; i < 2; i++)
                pf[i] = *(const bf16x8*)
                    &Ps[wave][(i * 16 + l16) * 128 + kb * 32 + quad * 8];
            #pragma unroll
            for (int db = 0; db < 4; db++) {
                const bf16x8 vf = *(const bf16x8*)
                    &Vs[(db * 16 + l16) * 128 + kb * 32 + quad * 8];
                #pragma unroll
                for (int i = 0; i < 2; i++)
                    o_acc[i][db] = __builtin_amdgcn_mfma_f32_16x16x32_bf16(
                        pf[i], vf, o_acc[i][db], 0, 0, 0);
            }
        }
    }

    #pragma unroll
    for (int i = 0; i < 2; i++)
        #pragma unroll
        for (int r = 0; r < 4; r++) {
            const float li = l_i[i][r];
            const float inv = (li > 0.f) ? 1.0f / li : 0.f;
            const int m = qw0 + i * 16 + quad * 4 + r;
            #pragma unroll
            for (int db = 0; db < 4; db++) {
                const int d = db * 16 + l16;
                Ctx[(size_t)m * EMB + h * DH + d] = f2bf(o_acc[i][db][r] * inv);
            }
        }
}

// ---------------------------------------------------------------------------
// Kernel 3: output projection, bf16 inputs, global_load_lds staging.
// ---------------------------------------------------------------------------
__global__ __launch_bounds__(256) void out_gemm(
    const short* __restrict__ A, const short* __restrict__ Wb,
    const float* __restrict__ Bias, float* __restrict__ Out)
{
    __shared__ __align__(16) short As[128 * 64];
    __shared__ __align__(16) short Bs[128 * 64];

    const int m0 = blockIdx.x * 128;
    const int n0 = blockIdx.y * 128;
    const int t = threadIdx.x;
    const int lane = t & 63, wave = t >> 6;
    const int quad = lane >> 4, l16 = lane & 15;
    const int wm = (wave >> 1) * 64, wn = (wave & 1) * 64;
    const int srow = lane >> 3, scol = (lane & 7) * 8;

    f32x4 acc[4][4] = {};

    for (int k0 = 0; k0 < EMB; k0 += 64) {
        #pragma unroll
        for (int qd = 0; qd < 4; qd++) {
            const int chunk = wave * 4 + qd;
            const int row = chunk * 8 + srow;
            gld_lds16(&A [(size_t)(m0 + row) * EMB + k0 + scol], &As[chunk * 512]);
            gld_lds16(&Wb[(size_t)(n0 + row) * EMB + k0 + scol], &Bs[chunk * 512]);
        }
        __syncthreads();

        #pragma unroll
        for (int kb = 0; kb < 2; kb++) {
            bf16x8 af[4], bfr[4];
            #pragma unroll
            for (int i = 0; i < 4; i++)
                af[i] = *(const bf16x8*)&As[(wm + i * 16 + l16) * 64 + kb * 32 + quad * 8];
            #pragma unroll
            for (int j = 0; j < 4; j++)
                bfr[j] = *(const bf16x8*)&Bs[(wn + j * 16 + l16) * 64 + kb * 32 + quad * 8];
            #pragma unroll
            for (int i = 0; i < 4; i++)
                #pragma unroll
                for (int j = 0; j < 4; j++)
                    acc[i][j] = __builtin_amdgcn_mfma_f32_16x16x32_bf16(
                        af[i], bfr[j], acc[i][j], 0, 0, 0);
        }
        __syncthreads();
    }

    #pragma unroll
    for (int j = 0; j < 4; j++) {
        const int n = n0 + wn + j * 16 + l16;
        const float bias = Bias[n];
        #pragma unroll
        for (int i = 0; i < 4; i++)
            #pragma unroll
            for (int r = 0; r < 4; r++) {
                const int m = m0 + wm + i * 16 + quad * 4 + r;
                Out[(size_t)m * EMB + n] = acc[i][j][r] + bias;
            }
    }
}

// ---------------------------------------------------------------------------
extern "C" void kernel_launch(void* const* d_in, const int* in_sizes, int n_in,
                              void* d_out, int out_size, void* d_ws, size_t ws_size,
                              hipStream_t stream)
{
    (void)in_sizes; (void)n_in; (void)out_size;
    const float* x     = (const float*)d_in[0];
    const float* w_qkv = (const float*)d_in[2];
    const float* b_qkv = (const float*)d_in[3];
    const float* w_out = (const float*)d_in[4];
    const float* b_out = (const float*)d_in[5];
    float* out = (float*)d_out;

    char* ws = (char*)d_ws;
    const size_t SEG = (size_t)NH * S_LEN * DH * sizeof(short);     // 6 MB
    short* Qw  = (short*)(ws);
    short* Kw  = (short*)(ws + SEG);
    short* Vt  = (short*)(ws + 2 * SEG);
    short* Ctx = (short*)(ws + 3 * SEG);
    const size_t OP_OFF = 4 * SEG;
    const size_t OP_SZ  = (size_t)NH * NCHUNK * S_LEN * DH * sizeof(short);
    const size_t ML_SZ  = (size_t)NH * NCHUNK * S_LEN * sizeof(float);
    short* Opart = (short*)(ws + OP_OFF);
    float* Mpart = (float*)(ws + OP_OFF + OP_SZ);
    float* Lpart = (float*)(ws + OP_OFF + OP_SZ + ML_SZ);
    const size_t need = OP_OFF + OP_SZ + 2 * ML_SZ;

    const int XN8 = (S_LEN * EMB) / 8;
    const int WQ8 = (3 * EMB * EMB) / 8;
    const int WO8 = (EMB * EMB) / 8;
    const size_t WO_BYTES = (size_t)EMB * EMB * sizeof(short);
    short* Xb    = (short*)(ws + OP_OFF);
    short* Wqkvb = (short*)(ws + OP_OFF + (size_t)XN8 * 8 * sizeof(short));
    const bool big = ws_size >= need + WO_BYTES;
    short* Woutb = big ? (short*)(ws + need) : (short*)(ws + OP_OFF);

    if (big) {
        const int tot8 = XN8 + WQ8 + WO8;
        cvt3_bf16<<<dim3((tot8 + 255) / 256), 256, 0, stream>>>(
            x, Xb, XN8, w_qkv, Wqkvb, WQ8, w_out, Woutb, WO8);
    } else {
        cvt_bf16<<<dim3((XN8 + 255) / 256), 256, 0, stream>>>(x, Xb, XN8);
        cvt_bf16<<<dim3((WQ8 + 255) / 256), 256, 0, stream>>>(w_qkv, Wqkvb, WQ8);
    }

    qkv_gemm<<<dim3(S_LEN / 128, (3 * EMB) / 128), 256, 0, stream>>>(
        Xb, Wqkvb, b_qkv, Qw, Kw, Vt);

    if (ws_size >= need) {
        flash_partial<<<dim3(S_LEN / 64, NH, NCHUNK), 256, 0, stream>>>(
            Qw, Kw, Vt, Opart, Mpart, Lpart);
        flash_merge<<<dim3(NH * S_LEN / 4), 256, 0, stream>>>(
            Opart, Mpart, Lpart, Ctx);
    } else {
        flash_attn<<<dim3(S_LEN / 128, NH), 256, 0, stream>>>(Qw, Kw, Vt, Ctx);
    }

    if (!big)
        cvt_bf16<<<dim3((WO8 + 255) / 256), 256, 0, stream>>>(w_out, Woutb, WO8);
    out_gemm<<<dim3(S_LEN / 128, EMB / 128), 256, 0, stream>>>(
        Ctx, Woutb, b_out, out);
}